// Round 7
// baseline (299.274 us; speedup 1.0000x reference)
//
#include <hip/hip_runtime.h>
#include <math.h>

// ---------------------------------------------------------------------------
// Round 18 — attention QBLK 64->128 (8-wave blocks): halve K/V staging,
// barriers, and fetch per q-row. Balanced pairing {bx,15-bx} (34 t-iters per
// block). Diag masking via global row/col compare on last two tiles; waves
// fully below the diagonal early-skip compute. T5 setprio around MFMA.
//   K0 (prep): X, Wqkv, Wout -> bf16; RoPE cos/sin tables.
//   K1: qkv GEMM (+table RoPE), gload_lds staging.
//   K2: flash attention (this round's change).
//   K3: out = att @ Woutb^T -> FP32.
// ---------------------------------------------------------------------------

typedef __attribute__((ext_vector_type(8))) __bf16 bf16x8;
typedef __attribute__((ext_vector_type(8))) short  short8;
typedef __attribute__((ext_vector_type(4))) short  s16x4;
typedef __attribute__((ext_vector_type(4))) float  f32x4;

#define MFMA16(a, b, c) __builtin_amdgcn_mfma_f32_16x16x32_bf16((a), (b), (c), 0, 0, 0)

static constexpr int    BATCH = 4;
static constexpr int    SEQ   = 2048;
static constexpr int    DIM   = 1024;
static constexpr int    NH    = 16;
static constexpr int    HD    = 64;
static constexpr size_t BHSD  = (size_t)BATCH * NH * SEQ * HD;  // 8388608
static constexpr float  NEGINF = -1e9f;
static constexpr int    PS_LD  = 72;   // padded k-stride for Ps (16B-aligned reads)

__device__ __forceinline__ short f2bf(float f) {
    union { float f; unsigned u; } v; v.f = f;
    unsigned r = v.u + 0x7fffu + ((v.u >> 16) & 1u);  // RNE
    return (short)(r >> 16);
}

__device__ __forceinline__ short8 cvt8(const f32x4 lo, const f32x4 hi) {
    short8 r;
    r[0] = f2bf(lo[0]); r[1] = f2bf(lo[1]); r[2] = f2bf(lo[2]); r[3] = f2bf(lo[3]);
    r[4] = f2bf(hi[0]); r[5] = f2bf(hi[1]); r[6] = f2bf(hi[2]); r[7] = f2bf(hi[3]);
    return r;
}

template <bool F32>
__device__ __forceinline__ short8 ld8(const void* p, size_t row, int K, int k) {
    if constexpr (F32) {
        const float* f = (const float*)p;
        f32x4 lo = *(const f32x4*)&f[row * (size_t)K + k];
        f32x4 hi = *(const f32x4*)&f[row * (size_t)K + k + 4];
        return cvt8(lo, hi);
    } else {
        const short* s = (const short*)p;
        return *(const short8*)&s[row * (size_t)K + k];
    }
}

// async HBM->LDS, 16 B per lane. LDS dest = wave-uniform base + lane*16.
__device__ __forceinline__ void gload16(const void* g, void* lds) {
    __builtin_amdgcn_global_load_lds(
        (const __attribute__((address_space(1))) void*)g,
        (__attribute__((address_space(3))) void*)lds, 16, 0, 0);
}

// ---------------------------------------------------------------------------
// K0: one-shot bf16 conversion of X/Wqkv/Wout + RoPE trig tables.
// ---------------------------------------------------------------------------
__global__ __launch_bounds__(256) void prep_kernel(
    const float* __restrict__ X, const float* __restrict__ Wq,
    const float* __restrict__ Wo, short* __restrict__ Xb,
    short* __restrict__ Wqb, short* __restrict__ Wob,
    float* __restrict__ cosT, float* __restrict__ sinT) {
    const int stride = gridDim.x * blockDim.x;
    for (int idx = blockIdx.x * blockDim.x + threadIdx.x; idx < 3211264; idx += stride) {
        if (idx < 3145728) {
            const float* src; short* dst; int off;
            if (idx < 2097152)      { src = X;  dst = Xb;  off = idx; }
            else if (idx < 2883584) { src = Wq; dst = Wqb; off = idx - 2097152; }
            else                    { src = Wo; dst = Wob; off = idx - 2883584; }
            f32x4 v = *(const f32x4*)&src[(size_t)off * 4];
            s16x4 r;
            r[0] = f2bf(v[0]); r[1] = f2bf(v[1]); r[2] = f2bf(v[2]); r[3] = f2bf(v[3]);
            *(s16x4*)&dst[(size_t)off * 4] = r;
        } else {
            int r = idx - 3145728;              // 0..65535
            int s = r >> 5, d = r & 31;
            float ang = (float)s * __expf(-0.28782313662425574f * (float)d);
            float sn, cs;
            sincosf(ang, &sn, &cs);
            cosT[r] = cs; sinT[r] = sn;
        }
    }
}

// ---------------------------------------------------------------------------
// GEMM core (fallback, reg-staged): C(128x128) += A(128xK) * B(128xK)^T.
// ---------------------------------------------------------------------------
template <bool AF32, bool BF32>
__device__ __forceinline__ void gemm128_core(
    const void* __restrict__ A, const void* __restrict__ B, int K,
    short* As, short* Bs, int bm, int bn, f32x4 acc[4][4]) {
    const int tid  = threadIdx.x;
    const int lane = tid & 63;
    const int wave = tid >> 6;
    const int quad = lane >> 4;
    const int col  = lane & 15;
    const int wm   = (wave & 1) * 64;
    const int wn   = (wave >> 1) * 64;

    const int r0 = tid >> 2;
    const int r1 = (tid + 256) >> 2;
    const int ko = (tid & 3) * 8;

#pragma unroll
    for (int i = 0; i < 4; ++i)
#pragma unroll
        for (int j = 0; j < 4; ++j) acc[i][j] = f32x4{0.f, 0.f, 0.f, 0.f};

#pragma unroll 1
    for (int k0 = 0; k0 < K; k0 += 32) {
        short8 a0 = ld8<AF32>(A, (size_t)(bm + r0), K, k0 + ko);
        short8 a1 = ld8<AF32>(A, (size_t)(bm + r1), K, k0 + ko);
        short8 b0 = ld8<BF32>(B, (size_t)(bn + r0), K, k0 + ko);
        short8 b1 = ld8<BF32>(B, (size_t)(bn + r1), K, k0 + ko);
        __syncthreads();
        *(short8*)&As[tid * 8]         = a0;
        *(short8*)&As[(tid + 256) * 8] = a1;
        *(short8*)&Bs[tid * 8]         = b0;
        *(short8*)&Bs[(tid + 256) * 8] = b1;
        __syncthreads();

        bf16x8 af[4], bfr[4];
#pragma unroll
        for (int i = 0; i < 4; ++i)
            af[i] = *(const bf16x8*)&As[(wm + i * 16 + col) * 32 + quad * 8];
#pragma unroll
        for (int j = 0; j < 4; ++j)
            bfr[j] = *(const bf16x8*)&Bs[(wn + j * 16 + col) * 32 + quad * 8];
#pragma unroll
        for (int i = 0; i < 4; ++i)
#pragma unroll
            for (int j = 0; j < 4; ++j)
                acc[i][j] = MFMA16(af[i], bfr[j], acc[i][j]);
    }
}

// ---------------------------------------------------------------------------
// GEMM core (bf16, global_load_lds staging — m97 structure).
// ---------------------------------------------------------------------------
__device__ __forceinline__ void gemm128_lds(
    const short* __restrict__ A, const short* __restrict__ B, int K,
    short* As, short* Bs, int bm, int bn, f32x4 acc[4][4]) {
    const int tid  = threadIdx.x;
    const int lane = tid & 63;
    const int wave = tid >> 6;
    const int quad = lane >> 4;
    const int col  = lane & 15;
    const int wm   = (wave & 1) * 64;
    const int wn   = (wave >> 1) * 64;

    const int r0 = tid >> 2;            // 0..63
    const int r1 = r0 + 64;             // 64..127
    const int ko = (tid & 3) * 8;

    const short* A0 = &A[(size_t)(bm + r0) * K + ko];
    const short* A1 = &A[(size_t)(bm + r1) * K + ko];
    const short* B0 = &B[(size_t)(bn + r0) * K + ko];
    const short* B1 = &B[(size_t)(bn + r1) * K + ko];

    short* As0 = &As[wave * 512];          // wave base, first half
    short* As1 = &As[2048 + wave * 512];   // second half (+4096 B)
    short* Bs0 = &Bs[wave * 512];
    short* Bs1 = &Bs[2048 + wave * 512];

#pragma unroll
    for (int i = 0; i < 4; ++i)
#pragma unroll
        for (int j = 0; j < 4; ++j) acc[i][j] = f32x4{0.f, 0.f, 0.f, 0.f};

#pragma unroll 1
    for (int k0 = 0; k0 < K; k0 += 32) {
        __syncthreads();                   // prev step's LDS reads done
        gload16(A0 + k0, As0);
        gload16(A1 + k0, As1);
        gload16(B0 + k0, Bs0);
        gload16(B1 + k0, Bs1);
        __syncthreads();                   // vmcnt drained -> tile staged

        bf16x8 af[4], bfr[4];
#pragma unroll
        for (int i = 0; i < 4; ++i)
            af[i] = *(const bf16x8*)&As[(wm + i * 16 + col) * 32 + quad * 8];
#pragma unroll
        for (int j = 0; j < 4; ++j)
            bfr[j] = *(const bf16x8*)&Bs[(wn + j * 16 + col) * 32 + quad * 8];
#pragma unroll
        for (int i = 0; i < 4; ++i)
#pragma unroll
            for (int j = 0; j < 4; ++j)
                acc[i][j] = MFMA16(af[i], bfr[j], acc[i][j]);
    }
}

// ---------------------------------------------------------------------------
// K1: QKV GEMM + RoPE. grid=(24, 64). Q,K row-major [B,H,S,D]; V transposed
// [B,H,D,S].
// ---------------------------------------------------------------------------
template <bool PRE>
__global__ __launch_bounds__(256, 2) void qkv_rope_kernel(
    const void* __restrict__ X, const void* __restrict__ W,
    const float* __restrict__ cosT, const float* __restrict__ sinT,
    short* __restrict__ Qo, short* __restrict__ Ko, short* __restrict__ VT) {
    __shared__ __align__(16) short As[128 * 32];
    __shared__ __align__(16) short Bs[128 * 32];
    const int bm = blockIdx.y * 128, bn = blockIdx.x * 128;
    const int lane = threadIdx.x & 63, wave = threadIdx.x >> 6;
    const int quad = lane >> 4, col = lane & 15;
    const int wm = (wave & 1) * 64, wn = (wave >> 1) * 64;

    f32x4 acc[4][4];
    if constexpr (PRE)
        gemm128_lds((const short*)X, (const short*)W, 1024, As, Bs, bm, bn, acc);
    else
        gemm128_core<true, true>(X, W, 1024, As, Bs, bm, bn, acc);

    const int n0    = bn + wn;       // 64-aligned -> which/h wave-uniform
    const int which = n0 >> 10;      // 0=q 1=k 2=v
    const int h     = (n0 >> 6) & 15;

    if (which == 2) {
        // V^T: VT[((b*NH+h)*HD + d)*SEQ + s], 4 consecutive s per 8B store
#pragma unroll
        for (int i = 0; i < 4; ++i) {
            int    m = bm + wm + i * 16 + quad * 4;    // s of reg 0
            int    b = m >> 11, s = m & 2047;
            size_t rowb = (size_t)(b * NH + h) * HD;
#pragma unroll
            for (int j = 0; j < 4; ++j) {
                int   d = j * 16 + col;
                s16x4 pk;
                pk[0] = f2bf(acc[i][j][0]); pk[1] = f2bf(acc[i][j][1]);
                pk[2] = f2bf(acc[i][j][2]); pk[3] = f2bf(acc[i][j][3]);
                *(s16x4*)&VT[(rowb + d) * SEQ + s] = pk;
            }
        }
    } else {
        short* dst = which ? Ko : Qo;
#pragma unroll
        for (int i = 0; i < 4; ++i)
#pragma unroll
            for (int reg = 0; reg < 4; ++reg) {
                int    m = bm + wm + i * 16 + quad * 4 + reg;
                int    b = m >> 11, s = m & 2047;
                size_t base = ((size_t)(b * NH + h) * SEQ + s) * HD;
#pragma unroll
                for (int j = 0; j < 2; ++j) {
                    int   d1 = j * 16 + col;                        // 0..31
                    float sn, cs;
                    if constexpr (PRE) {
                        cs = cosT[(s << 5) + d1];
                        sn = sinT[(s << 5) + d1];
                    } else {
                        float inv = __expf(-0.28782313662425574f * (float)d1);
                        sincosf((float)s * inv, &sn, &cs);
                    }
                    float x1 = acc[i][j][reg];
                    float x2 = acc[i][j + 2][reg];
                    dst[base + d1]      = f2bf(x1 * cs - x2 * sn);
                    dst[base + d1 + 32] = f2bf(x1 * sn + x2 * cs);
                }
            }
    }
}

// ---------------------------------------------------------------------------
// K2: causal flash attention. 512 threads / 8 waves; QBLK=128 (wave w owns
// q-rows qt*128 + w*16 .. +15). grid=(8, 16, 4); block handles q-tile pair
// {bx, 15-bx} -> exactly 34 t-iterations (balanced). K/V staging + barriers
// + fetch per q-row HALVED vs QBLK=64. Kt/Vt XOR-swizzled. Masking: global
// row/col compare on tiles t >= 2*qt; waves fully below diagonal skip
// compute (barriers outside the skip). Softmax: defer-max THR=8 +
// per-lane partial l_i. T5 setprio around MFMA clusters.
// ---------------------------------------------------------------------------
__global__ __launch_bounds__(512, 2) void attn_kernel(
    const short* __restrict__ Q, const short* __restrict__ K,
    const short* __restrict__ VT, short* __restrict__ att) {
    const int b = blockIdx.z, h = blockIdx.y;
    const int tid = threadIdx.x, wave = tid >> 6, lane = tid & 63;
    const int quad = lane >> 4, col = lane & 15;
    const size_t hoff = (size_t)(b * NH + h) * SEQ * HD;
    const short* Qp  = Q + hoff;
    const short* Kp  = K + hoff;
    const short* VTp = VT + hoff;   // [HD][SEQ]

    __shared__ __align__(16) short Kt[64 * 64];        // [t][d], swizzled
    __shared__ __align__(16) short Vt[64 * 64];        // [d][t], swizzled
    __shared__ __align__(16) short Ps[8 * 16 * PS_LD]; // per-wave P [m][k], padded

    const int r  = tid >> 3;            // 0..63 (512 threads -> one row each)
    const int c8 = (tid & 7) * 8;
    const int cs = c8 ^ ((r & 7) << 3);             // swizzled store column
    const int swc = (col & 7) << 3;
    const int cA  = (quad * 8) ^ swc;               // first half of row
    const int cB  = (32 + quad * 8) ^ swc;          // second half of row
    short* Pw = &Ps[wave * 16 * PS_LD];

#pragma unroll 1
    for (int pass = 0; pass < 2; ++pass) {
        const int qt   = pass ? 15 - (int)blockIdx.x : (int)blockIdx.x;
        const int q0   = qt * 128 + wave * 16;      // this wave's first q-row
        const int tmax = 2 * qt + 1;

        bf16x8 aq0 = *(const bf16x8*)&Qp[(q0 + col) * HD + quad * 8];
        bf16x8 aq1 = *(const bf16x8*)&Qp[(q0 + col) * HD + 32 + quad * 8];

        float m_i[4], l_i[4];
        f32x4 o[4];
#pragma unroll
        for (int rr = 0; rr < 4; ++rr) { m_i[rr] = NEGINF; l_i[rr] = 0.f; o[rr] = f32x4{0.f, 0.f, 0.f, 0.f}; }

        // prefetch tile 0
        short8 ka = *(const short8*)&Kp[r * HD + c8];
        short8 va = *(const short8*)&VTp[(size_t)r * SEQ + c8];

#pragma unroll 1
        for (int t = 0; t <= tmax; ++t) {
            const int kt = t * 64;
            __syncthreads();                       // prev iter's LDS reads done
            *(short8*)&Kt[r * 64 + cs] = ka;
            *(short8*)&Vt[r * 64 + cs] = va;
            __syncthreads();                       // tile staged

            if (t < tmax) {                        // prefetch next tile
                const int kn = kt + 64;
                ka = *(const short8*)&Kp[(kn + r) * HD + c8];
                va = *(const short8*)&VTp[(size_t)r * SEQ + kn + c8];
            }

            if (kt > q0 + 15) continue;            // wave fully masked

            // S = Q K^T / 8; mask only on the last two tiles of the pass
            float p[4][4];  // [jn][reg]
            __builtin_amdgcn_s_setprio(1);
#pragma unroll
            for (int jn = 0; jn < 4; ++jn) {
                f32x4  s  = f32x4{0.f, 0.f, 0.f, 0.f};
                bf16x8 b0 = *(const bf16x8*)&Kt[(jn * 16 + col) * 64 + cA];
                bf16x8 b1 = *(const bf16x8*)&Kt[(jn * 16 + col) * 64 + cB];
                s = MFMA16(aq0, b0, s);
                s = MFMA16(aq1, b1, s);
                if (t >= 2 * qt) {                 // wave-uniform branch
#pragma unroll
                    for (int reg = 0; reg < 4; ++reg) {
                        int qr = q0 + quad * 4 + reg;          // global row
                        int kc = kt + jn * 16 + col;           // global col
                        p[jn][reg] = (kc <= qr) ? s[reg] * 0.125f : NEGINF;
                    }
                } else {
#pragma unroll
                    for (int reg = 0; reg < 4; ++reg) p[jn][reg] = s[reg] * 0.125f;
                }
            }
            __builtin_amdgcn_s_setprio(0);

            // --- softmax: defer-max (THR=8) + per-lane partial l_i ---
            float lm[4];
#pragma unroll
            for (int reg = 0; reg < 4; ++reg)
                lm[reg] = fmaxf(fmaxf(p[0][reg], p[1][reg]), fmaxf(p[2][reg], p[3][reg]));
            int ok = (lm[0] <= m_i[0] + 8.f) & (lm[1] <= m_i[1] + 8.f) &
                     (lm[2] <= m_i[2] + 8.f) & (lm[3] <= m_i[3] + 8.f);
            if (__all(ok)) {
                // cheap path: no max-reduce, no alpha, no rescale
#pragma unroll
                for (int reg = 0; reg < 4; ++reg) {
                    float rs = 0.f;
#pragma unroll
                    for (int jn = 0; jn < 4; ++jn) {
                        p[jn][reg] = __expf(p[jn][reg] - m_i[reg]);
                        rs += p[jn][reg];
                    }
                    l_i[reg] += rs;                // per-lane partial
                }
            } else {
                float alpha[4];
#pragma unroll
                for (int reg = 0; reg < 4; ++reg) {
                    float mx = lm[reg];
#pragma unroll
                    for (int off = 8; off >= 1; off >>= 1) mx = fmaxf(mx, __shfl_xor(mx, off, 64));
                    float mn   = fmaxf(m_i[reg], mx);
                    alpha[reg] = __expf(m_i[reg] - mn);
                    float rs = 0.f;
#pragma unroll
                    for (int jn = 0; jn < 4; ++jn) {
                        p[jn][reg] = __expf(p[jn][reg] - mn);
                        rs += p[jn][reg];
                    }
                    l_i[reg] = l_i[reg] * alpha[reg] + rs;   // per-lane partial
                    m_i[reg] = mn;
                }
#pragma unroll
                for (int jd = 0; jd < 4; ++jd)
#pragma unroll
                    for (int reg = 0; reg < 4; ++reg) o[jd][reg] *= alpha[reg];
            }

            // P: C-layout -> wave-private LDS [m][k] (padded stride; no barrier)
#pragma unroll
            for (int jn = 0; jn < 4; ++jn)
#pragma unroll
                for (int reg = 0; reg < 4; ++reg)
                    Pw[(quad * 4 + reg) * PS_LD + jn * 16 + col] = f2bf(p[jn][reg]);

            // O += P V
            bf16x8 ap0 = *(const bf16x8*)&Pw[col * PS_LD + quad * 8];
            bf16x8 ap1 = *(const bf16x8*)&Pw[col * PS_LD + 32 + quad * 8];
            __builtin_amdgcn_s_setprio(1);
#pragma unroll
            for (int jd = 0; jd < 4; ++jd) {
                bf16x8 bv0 = *(const bf16x8*)&Vt[(jd * 16 + col) * 64 + cA];
                bf16x8 bv1 = *(const bf16x8*)&Vt[(jd * 16 + col) * 64 + cB];
                o[jd] = MFMA16(ap0, bv0, o[jd]);
                o[jd] = MFMA16(ap1, bv1, o[jd]);
            }
            __builtin_amdgcn_s_setprio(0);
        }

        // epilogue: reduce per-lane l partials across the 16 col-lanes, then
        // att[b, s, h*64 + d] bf16
#pragma unroll
        for (int off = 8; off >= 1; off >>= 1)
#pragma unroll
            for (int reg = 0; reg < 4; ++reg)
                l_i[reg] += __shfl_xor(l_i[reg], off, 64);
        float inv_l[4];
#pragma unroll
        for (int reg = 0; reg < 4; ++reg) inv_l[reg] = 1.f / l_i[reg];
#pragma unroll
        for (int jd = 0; jd < 4; ++jd)
#pragma unroll
            for (int reg = 0; reg < 4; ++reg) {
                int s = q0 + quad * 4 + reg;
                att[((size_t)(b * SEQ + s)) * DIM + h * HD + jd * 16 + col] =
                    f2bf(o[jd][reg] * inv_l[reg]);
            }
    }
}

// ---------------------------------------------------------------------------
// K3: out = att @ Wout^T, FP32 output. grid=(8, 64). PRE: bf16 Wout + gload.
// ---------------------------------------------------------------------------
template <bool PRE>
__global__ __launch_bounds__(256, 2) void out_gemm_kernel(
    const short* __restrict__ A, const void* __restrict__ W,
    float* __restrict__ out) {
    __shared__ __align__(16) short As[128 * 32];
    __shared__ __align__(16) short Bs[128 * 32];
    const int bm = blockIdx.y * 128, bn = blockIdx.x * 128;
    const int lane = threadIdx.x & 63, wave = threadIdx.x >> 6;
    const int quad = lane >> 4, col = lane & 15;
    const int wm = (wave & 1) * 64, wn = (wave >> 1) * 64;

    f32x4 acc[4][4];
    if constexpr (PRE)
        gemm128_lds(A, (const short*)W, 1024, As, Bs, bm, bn, acc);
    else
        gemm128_core<false, true>(A, W, 1024, As, Bs, bm, bn, acc);

#pragma unroll
    for (int i = 0; i < 4; ++i)
#pragma unroll
        for (int reg = 0; reg < 4; ++reg) {
            int    m    = bm + wm + i * 16 + quad * 4 + reg;
            size_t base = (size_t)m * DIM + bn + wn;
#pragma unroll
            for (int j = 0; j < 4; ++j)
                out[base + j * 16 + col] = acc[i][j][reg];   // FP32 store
        }
}

// ---------------------------------------------------------------------------
extern "C" void kernel_launch(void* const* d_in, const int* in_sizes, int n_in,
                              void* d_out, int out_size, void* d_ws, size_t ws_size,
                              hipStream_t stream) {
    // Pointer assignment by unique element counts:
    //   x=8388608, mask=4194304 (tril, unused), Wqkv=3145728, Wout=1048576
    const float* x    = nullptr;
    const float* Wqkv = nullptr;
    const float* Wout = nullptr;
    for (int i = 0; i < n_in; ++i) {
        switch (in_sizes[i]) {
            case 8388608: x    = (const float*)d_in[i]; break;
            case 3145728: Wqkv = (const float*)d_in[i]; break;
            case 1048576: Wout = (const float*)d_in[i]; break;
            default: break;
        }
    }
    if (!x || !Wqkv || !Wout) return;

    short* Q  = (short*)d_ws;           // 16 MiB
    short* K  = Q + BHSD;               // 16 MiB
    short* VT = K + BHSD;               // 16 MiB (V transposed [B,H,D,S])
    float* out = (float*)d_out;

    const size_t need_pre = (size_t)4 * BHSD * sizeof(short)   // Q,K,VT,att
                          + BHSD * sizeof(short)               // Xb
                          + (size_t)3145728 * sizeof(short)    // Wqkvb
                          + (size_t)1048576 * sizeof(short)    // Woutb
                          + (size_t)2 * 65536 * sizeof(float); // tables

    if (ws_size >= need_pre) {
        short* att  = VT + BHSD;
        short* Xb   = att + BHSD;
        short* Wqb  = Xb + BHSD;
        short* Wob  = Wqb + 3145728;
        float* cosT = (float*)(Wob + 1048576);
        float* sinT = cosT + 65536;

        prep_kernel<<<dim3(2048), 256, 0, stream>>>(x, Wqkv, Wout, Xb, Wqb, Wob, cosT, sinT);
        qkv_rope_kernel<true><<<dim3(24, 64), 256, 0, stream>>>(Xb, Wqb, cosT, sinT, Q, K, VT);
        attn_kernel<<<dim3(8, NH, BATCH), 512, 0, stream>>>(Q, K, VT, att);
        out_gemm_kernel<true><<<dim3(8, 64), 256, 0, stream>>>(att, Wob, out);
    } else {
        // Fallback: fp32 staging + inline RoPE.
        qkv_rope_kernel<false><<<dim3(24, 64), 256, 0, stream>>>(
            x, Wqkv, nullptr, nullptr, Q, K, VT);

        const bool direct = ws_size >= (size_t)4 * BHSD * sizeof(short);
        short* att_dst = direct ? (VT + BHSD) : (short*)d_out;
        attn_kernel<<<dim3(8, NH, BATCH), 512, 0, stream>>>(Q, K, VT, att_dst);

        short* att = att_dst;
        if (!direct) {
            att = (short*)d_ws;         // reuse Q region after K2
            hipMemcpyAsync(att, att_dst, BHSD * sizeof(short), hipMemcpyDeviceToDevice, stream);
        }
        out_gemm_kernel<false><<<dim3(8, 64), 256, 0, stream>>>(att, Wout, out);
    }
}

// Round 8
// 287.464 us; speedup vs baseline: 1.0411x; 1.0411x over previous
//
#include <hip/hip_runtime.h>
#include <math.h>

// ---------------------------------------------------------------------------
// Round 19 — attention fragment-read amortization (LDS-throughput model).
//   K2: 4 waves x 32 q-rows (QBLK=128, 256 thr). Per jn/jd the K/V LDS
//   fragment is read ONCE and consumed by two 16-row strips in registers ->
//   K/V fragment bytes per q-row HALVE (the dominant LDS term, ~16KB/wave/
//   tile). Staging/barriers/fetch per q-row also halve. Round-18's 8x16
//   failed because it left per-wave fragment bytes per q-row unchanged.
//   K0/K1/K3 unchanged (prep, gload_lds GEMM + table RoPE, out GEMM).
// ---------------------------------------------------------------------------

typedef __attribute__((ext_vector_type(8))) __bf16 bf16x8;
typedef __attribute__((ext_vector_type(8))) short  short8;
typedef __attribute__((ext_vector_type(4))) short  s16x4;
typedef __attribute__((ext_vector_type(4))) float  f32x4;

#define MFMA16(a, b, c) __builtin_amdgcn_mfma_f32_16x16x32_bf16((a), (b), (c), 0, 0, 0)

static constexpr int    BATCH = 4;
static constexpr int    SEQ   = 2048;
static constexpr int    DIM   = 1024;
static constexpr int    NH    = 16;
static constexpr int    HD    = 64;
static constexpr size_t BHSD  = (size_t)BATCH * NH * SEQ * HD;  // 8388608
static constexpr float  NEGINF = -1e9f;
static constexpr int    PS_LD  = 72;   // padded k-stride for Ps (16B-aligned reads)

__device__ __forceinline__ short f2bf(float f) {
    union { float f; unsigned u; } v; v.f = f;
    unsigned r = v.u + 0x7fffu + ((v.u >> 16) & 1u);  // RNE
    return (short)(r >> 16);
}

__device__ __forceinline__ short8 cvt8(const f32x4 lo, const f32x4 hi) {
    short8 r;
    r[0] = f2bf(lo[0]); r[1] = f2bf(lo[1]); r[2] = f2bf(lo[2]); r[3] = f2bf(lo[3]);
    r[4] = f2bf(hi[0]); r[5] = f2bf(hi[1]); r[6] = f2bf(hi[2]); r[7] = f2bf(hi[3]);
    return r;
}

template <bool F32>
__device__ __forceinline__ short8 ld8(const void* p, size_t row, int K, int k) {
    if constexpr (F32) {
        const float* f = (const float*)p;
        f32x4 lo = *(const f32x4*)&f[row * (size_t)K + k];
        f32x4 hi = *(const f32x4*)&f[row * (size_t)K + k + 4];
        return cvt8(lo, hi);
    } else {
        const short* s = (const short*)p;
        return *(const short8*)&s[row * (size_t)K + k];
    }
}

// async HBM->LDS, 16 B per lane. LDS dest = wave-uniform base + lane*16.
__device__ __forceinline__ void gload16(const void* g, void* lds) {
    __builtin_amdgcn_global_load_lds(
        (const __attribute__((address_space(1))) void*)g,
        (__attribute__((address_space(3))) void*)lds, 16, 0, 0);
}

// ---------------------------------------------------------------------------
// K0: one-shot bf16 conversion of X/Wqkv/Wout + RoPE trig tables.
// ---------------------------------------------------------------------------
__global__ __launch_bounds__(256) void prep_kernel(
    const float* __restrict__ X, const float* __restrict__ Wq,
    const float* __restrict__ Wo, short* __restrict__ Xb,
    short* __restrict__ Wqb, short* __restrict__ Wob,
    float* __restrict__ cosT, float* __restrict__ sinT) {
    const int stride = gridDim.x * blockDim.x;
    for (int idx = blockIdx.x * blockDim.x + threadIdx.x; idx < 3211264; idx += stride) {
        if (idx < 3145728) {
            const float* src; short* dst; int off;
            if (idx < 2097152)      { src = X;  dst = Xb;  off = idx; }
            else if (idx < 2883584) { src = Wq; dst = Wqb; off = idx - 2097152; }
            else                    { src = Wo; dst = Wob; off = idx - 2883584; }
            f32x4 v = *(const f32x4*)&src[(size_t)off * 4];
            s16x4 r;
            r[0] = f2bf(v[0]); r[1] = f2bf(v[1]); r[2] = f2bf(v[2]); r[3] = f2bf(v[3]);
            *(s16x4*)&dst[(size_t)off * 4] = r;
        } else {
            int r = idx - 3145728;              // 0..65535
            int s = r >> 5, d = r & 31;
            float ang = (float)s * __expf(-0.28782313662425574f * (float)d);
            float sn, cs;
            sincosf(ang, &sn, &cs);
            cosT[r] = cs; sinT[r] = sn;
        }
    }
}

// ---------------------------------------------------------------------------
// GEMM core (fallback, reg-staged): C(128x128) += A(128xK) * B(128xK)^T.
// ---------------------------------------------------------------------------
template <bool AF32, bool BF32>
__device__ __forceinline__ void gemm128_core(
    const void* __restrict__ A, const void* __restrict__ B, int K,
    short* As, short* Bs, int bm, int bn, f32x4 acc[4][4]) {
    const int tid  = threadIdx.x;
    const int lane = tid & 63;
    const int wave = tid >> 6;
    const int quad = lane >> 4;
    const int col  = lane & 15;
    const int wm   = (wave & 1) * 64;
    const int wn   = (wave >> 1) * 64;

    const int r0 = tid >> 2;
    const int r1 = (tid + 256) >> 2;
    const int ko = (tid & 3) * 8;

#pragma unroll
    for (int i = 0; i < 4; ++i)
#pragma unroll
        for (int j = 0; j < 4; ++j) acc[i][j] = f32x4{0.f, 0.f, 0.f, 0.f};

#pragma unroll 1
    for (int k0 = 0; k0 < K; k0 += 32) {
        short8 a0 = ld8<AF32>(A, (size_t)(bm + r0), K, k0 + ko);
        short8 a1 = ld8<AF32>(A, (size_t)(bm + r1), K, k0 + ko);
        short8 b0 = ld8<BF32>(B, (size_t)(bn + r0), K, k0 + ko);
        short8 b1 = ld8<BF32>(B, (size_t)(bn + r1), K, k0 + ko);
        __syncthreads();
        *(short8*)&As[tid * 8]         = a0;
        *(short8*)&As[(tid + 256) * 8] = a1;
        *(short8*)&Bs[tid * 8]         = b0;
        *(short8*)&Bs[(tid + 256) * 8] = b1;
        __syncthreads();

        bf16x8 af[4], bfr[4];
#pragma unroll
        for (int i = 0; i < 4; ++i)
            af[i] = *(const bf16x8*)&As[(wm + i * 16 + col) * 32 + quad * 8];
#pragma unroll
        for (int j = 0; j < 4; ++j)
            bfr[j] = *(const bf16x8*)&Bs[(wn + j * 16 + col) * 32 + quad * 8];
#pragma unroll
        for (int i = 0; i < 4; ++i)
#pragma unroll
            for (int j = 0; j < 4; ++j)
                acc[i][j] = MFMA16(af[i], bfr[j], acc[i][j]);
    }
}

// ---------------------------------------------------------------------------
// GEMM core (bf16, global_load_lds staging — m97 structure).
// ---------------------------------------------------------------------------
__device__ __forceinline__ void gemm128_lds(
    const short* __restrict__ A, const short* __restrict__ B, int K,
    short* As, short* Bs, int bm, int bn, f32x4 acc[4][4]) {
    const int tid  = threadIdx.x;
    const int lane = tid & 63;
    const int wave = tid >> 6;
    const int quad = lane >> 4;
    const int col  = lane & 15;
    const int wm   = (wave & 1) * 64;
    const int wn   = (wave >> 1) * 64;

    const int r0 = tid >> 2;            // 0..63
    const int r1 = r0 + 64;             // 64..127
    const int ko = (tid & 3) * 8;

    const short* A0 = &A[(size_t)(bm + r0) * K + ko];
    const short* A1 = &A[(size_t)(bm + r1) * K + ko];
    const short* B0 = &B[(size_t)(bn + r0) * K + ko];
    const short* B1 = &B[(size_t)(bn + r1) * K + ko];

    short* As0 = &As[wave * 512];          // wave base, first half
    short* As1 = &As[2048 + wave * 512];   // second half (+4096 B)
    short* Bs0 = &Bs[wave * 512];
    short* Bs1 = &Bs[2048 + wave * 512];

#pragma unroll
    for (int i = 0; i < 4; ++i)
#pragma unroll
        for (int j = 0; j < 4; ++j) acc[i][j] = f32x4{0.f, 0.f, 0.f, 0.f};

#pragma unroll 1
    for (int k0 = 0; k0 < K; k0 += 32) {
        __syncthreads();                   // prev step's LDS reads done
        gload16(A0 + k0, As0);
        gload16(A1 + k0, As1);
        gload16(B0 + k0, Bs0);
        gload16(B1 + k0, Bs1);
        __syncthreads();                   // vmcnt drained -> tile staged

        bf16x8 af[4], bfr[4];
#pragma unroll
        for (int i = 0; i < 4; ++i)
            af[i] = *(const bf16x8*)&As[(wm + i * 16 + col) * 32 + quad * 8];
#pragma unroll
        for (int j = 0; j < 4; ++j)
            bfr[j] = *(const bf16x8*)&Bs[(wn + j * 16 + col) * 32 + quad * 8];
#pragma unroll
        for (int i = 0; i < 4; ++i)
#pragma unroll
            for (int j = 0; j < 4; ++j)
                acc[i][j] = MFMA16(af[i], bfr[j], acc[i][j]);
    }
}

// ---------------------------------------------------------------------------
// K1: QKV GEMM + RoPE. grid=(24, 64). Q,K row-major [B,H,S,D]; V transposed
// [B,H,D,S].
// ---------------------------------------------------------------------------
template <bool PRE>
__global__ __launch_bounds__(256, 2) void qkv_rope_kernel(
    const void* __restrict__ X, const void* __restrict__ W,
    const float* __restrict__ cosT, const float* __restrict__ sinT,
    short* __restrict__ Qo, short* __restrict__ Ko, short* __restrict__ VT) {
    __shared__ __align__(16) short As[128 * 32];
    __shared__ __align__(16) short Bs[128 * 32];
    const int bm = blockIdx.y * 128, bn = blockIdx.x * 128;
    const int lane = threadIdx.x & 63, wave = threadIdx.x >> 6;
    const int quad = lane >> 4, col = lane & 15;
    const int wm = (wave & 1) * 64, wn = (wave >> 1) * 64;

    f32x4 acc[4][4];
    if constexpr (PRE)
        gemm128_lds((const short*)X, (const short*)W, 1024, As, Bs, bm, bn, acc);
    else
        gemm128_core<true, true>(X, W, 1024, As, Bs, bm, bn, acc);

    const int n0    = bn + wn;       // 64-aligned -> which/h wave-uniform
    const int which = n0 >> 10;      // 0=q 1=k 2=v
    const int h     = (n0 >> 6) & 15;

    if (which == 2) {
        // V^T: VT[((b*NH+h)*HD + d)*SEQ + s], 4 consecutive s per 8B store
#pragma unroll
        for (int i = 0; i < 4; ++i) {
            int    m = bm + wm + i * 16 + quad * 4;    // s of reg 0
            int    b = m >> 11, s = m & 2047;
            size_t rowb = (size_t)(b * NH + h) * HD;
#pragma unroll
            for (int j = 0; j < 4; ++j) {
                int   d = j * 16 + col;
                s16x4 pk;
                pk[0] = f2bf(acc[i][j][0]); pk[1] = f2bf(acc[i][j][1]);
                pk[2] = f2bf(acc[i][j][2]); pk[3] = f2bf(acc[i][j][3]);
                *(s16x4*)&VT[(rowb + d) * SEQ + s] = pk;
            }
        }
    } else {
        short* dst = which ? Ko : Qo;
#pragma unroll
        for (int i = 0; i < 4; ++i)
#pragma unroll
            for (int reg = 0; reg < 4; ++reg) {
                int    m = bm + wm + i * 16 + quad * 4 + reg;
                int    b = m >> 11, s = m & 2047;
                size_t base = ((size_t)(b * NH + h) * SEQ + s) * HD;
#pragma unroll
                for (int j = 0; j < 2; ++j) {
                    int   d1 = j * 16 + col;                        // 0..31
                    float sn, cs;
                    if constexpr (PRE) {
                        cs = cosT[(s << 5) + d1];
                        sn = sinT[(s << 5) + d1];
                    } else {
                        float inv = __expf(-0.28782313662425574f * (float)d1);
                        sincosf((float)s * inv, &sn, &cs);
                    }
                    float x1 = acc[i][j][reg];
                    float x2 = acc[i][j + 2][reg];
                    dst[base + d1]      = f2bf(x1 * cs - x2 * sn);
                    dst[base + d1 + 32] = f2bf(x1 * sn + x2 * cs);
                }
            }
    }
}

// ---------------------------------------------------------------------------
// K2: causal flash attention. 256 threads / 4 waves; wave owns 32 q-rows
// (two 16-row strips) -> QBLK=128. grid=(8, 16, 4); pairing {bx, 15-bx}
// -> exactly 34 t-iterations (balanced). Per jn/jd the K/V fragment is read
// from LDS once and used by both strips (register reuse) -> K/V LDS bytes
// per q-row halved vs round-17. Kt/Vt XOR-swizzled. Diag masking via global
// compare on t >= 2*qt; fully-masked waves skip compute. Softmax: defer-max
// THR=8 + per-lane partial l_i, per strip. T5 setprio around MFMA.
// ---------------------------------------------------------------------------
__global__ __launch_bounds__(256, 2) void attn_kernel(
    const short* __restrict__ Q, const short* __restrict__ K,
    const short* __restrict__ VT, short* __restrict__ att) {
    const int b = blockIdx.z, h = blockIdx.y;
    const int tid = threadIdx.x, wave = tid >> 6, lane = tid & 63;
    const int quad = lane >> 4, col = lane & 15;
    const size_t hoff = (size_t)(b * NH + h) * SEQ * HD;
    const short* Qp  = Q + hoff;
    const short* Kp  = K + hoff;
    const short* VTp = VT + hoff;   // [HD][SEQ]

    __shared__ __align__(16) short Kt[64 * 64];        // [t][d], swizzled
    __shared__ __align__(16) short Vt[64 * 64];        // [d][t], swizzled
    __shared__ __align__(16) short Ps[4 * 32 * PS_LD]; // per-wave P [32][k], padded

    const int r0 = tid >> 3;            // 0..31
    const int r1 = r0 + 32;             // 32..63  (r1&7 == r0&7)
    const int c8 = (tid & 7) * 8;
    const int cs = c8 ^ ((r0 & 7) << 3);            // swizzled store column
    const int swc = (col & 7) << 3;
    const int cA  = (quad * 8) ^ swc;               // first half of row
    const int cB  = (32 + quad * 8) ^ swc;          // second half of row
    short* Pw = &Ps[wave * 32 * PS_LD];

#pragma unroll 1
    for (int pass = 0; pass < 2; ++pass) {
        const int qt   = pass ? 15 - (int)blockIdx.x : (int)blockIdx.x;
        const int q0   = qt * 128 + wave * 32;      // wave's first q-row
        const int tmax = 2 * qt + 1;

        // Q fragments for both strips (s2 = 0,1)
        bf16x8 aq[2][2];
#pragma unroll
        for (int s2 = 0; s2 < 2; ++s2) {
            aq[s2][0] = *(const bf16x8*)&Qp[(q0 + s2 * 16 + col) * HD + quad * 8];
            aq[s2][1] = *(const bf16x8*)&Qp[(q0 + s2 * 16 + col) * HD + 32 + quad * 8];
        }

        float m_i[2][4], l_i[2][4];
        f32x4 o[2][4];
#pragma unroll
        for (int s2 = 0; s2 < 2; ++s2)
#pragma unroll
            for (int rr = 0; rr < 4; ++rr) {
                m_i[s2][rr] = NEGINF; l_i[s2][rr] = 0.f;
                o[s2][rr] = f32x4{0.f, 0.f, 0.f, 0.f};
            }

        // prefetch tile 0
        short8 ka = *(const short8*)&Kp[r0 * HD + c8];
        short8 kb = *(const short8*)&Kp[r1 * HD + c8];
        short8 va = *(const short8*)&VTp[(size_t)r0 * SEQ + c8];
        short8 vb = *(const short8*)&VTp[(size_t)r1 * SEQ + c8];

#pragma unroll 1
        for (int t = 0; t <= tmax; ++t) {
            const int kt = t * 64;
            __syncthreads();                       // prev iter's LDS reads done
            *(short8*)&Kt[r0 * 64 + cs] = ka;
            *(short8*)&Kt[r1 * 64 + cs] = kb;
            *(short8*)&Vt[r0 * 64 + cs] = va;
            *(short8*)&Vt[r1 * 64 + cs] = vb;
            __syncthreads();                       // tile staged

            if (t < tmax) {                        // prefetch next tile
                const int kn = kt + 64;
                ka = *(const short8*)&Kp[(kn + r0) * HD + c8];
                kb = *(const short8*)&Kp[(kn + r1) * HD + c8];
                va = *(const short8*)&VTp[(size_t)r0 * SEQ + kn + c8];
                vb = *(const short8*)&VTp[(size_t)r1 * SEQ + kn + c8];
            }

            if (kt > q0 + 31) continue;            // wave fully masked

            // S = Q K^T / 8: K-fragment read once per jn, used by BOTH strips
            float p[2][4][4];  // [s2][jn][reg]
            __builtin_amdgcn_s_setprio(1);
#pragma unroll
            for (int jn = 0; jn < 4; ++jn) {
                bf16x8 b0 = *(const bf16x8*)&Kt[(jn * 16 + col) * 64 + cA];
                bf16x8 b1 = *(const bf16x8*)&Kt[(jn * 16 + col) * 64 + cB];
#pragma unroll
                for (int s2 = 0; s2 < 2; ++s2) {
                    f32x4 s = f32x4{0.f, 0.f, 0.f, 0.f};
                    s = MFMA16(aq[s2][0], b0, s);
                    s = MFMA16(aq[s2][1], b1, s);
                    if (t >= 2 * qt) {             // wave-uniform branch
#pragma unroll
                        for (int reg = 0; reg < 4; ++reg) {
                            int qr = q0 + s2 * 16 + quad * 4 + reg;  // global row
                            int kc = kt + jn * 16 + col;             // global col
                            p[s2][jn][reg] = (kc <= qr) ? s[reg] * 0.125f : NEGINF;
                        }
                    } else {
#pragma unroll
                        for (int reg = 0; reg < 4; ++reg)
                            p[s2][jn][reg] = s[reg] * 0.125f;
                    }
                }
            }
            __builtin_amdgcn_s_setprio(0);

            // --- softmax per strip: defer-max (THR=8) + per-lane partial l ---
#pragma unroll
            for (int s2 = 0; s2 < 2; ++s2) {
                float lm[4];
#pragma unroll
                for (int reg = 0; reg < 4; ++reg)
                    lm[reg] = fmaxf(fmaxf(p[s2][0][reg], p[s2][1][reg]),
                                    fmaxf(p[s2][2][reg], p[s2][3][reg]));
                int ok = (lm[0] <= m_i[s2][0] + 8.f) & (lm[1] <= m_i[s2][1] + 8.f) &
                         (lm[2] <= m_i[s2][2] + 8.f) & (lm[3] <= m_i[s2][3] + 8.f);
                if (__all(ok)) {
#pragma unroll
                    for (int reg = 0; reg < 4; ++reg) {
                        float rs = 0.f;
#pragma unroll
                        for (int jn = 0; jn < 4; ++jn) {
                            p[s2][jn][reg] = __expf(p[s2][jn][reg] - m_i[s2][reg]);
                            rs += p[s2][jn][reg];
                        }
                        l_i[s2][reg] += rs;
                    }
                } else {
                    float alpha[4];
#pragma unroll
                    for (int reg = 0; reg < 4; ++reg) {
                        float mx = lm[reg];
#pragma unroll
                        for (int off = 8; off >= 1; off >>= 1)
                            mx = fmaxf(mx, __shfl_xor(mx, off, 64));
                        float mn   = fmaxf(m_i[s2][reg], mx);
                        alpha[reg] = __expf(m_i[s2][reg] - mn);
                        float rs = 0.f;
#pragma unroll
                        for (int jn = 0; jn < 4; ++jn) {
                            p[s2][jn][reg] = __expf(p[s2][jn][reg] - mn);
                            rs += p[s2][jn][reg];
                        }
                        l_i[s2][reg] = l_i[s2][reg] * alpha[reg] + rs;
                        m_i[s2][reg] = mn;
                    }
#pragma unroll
                    for (int jd = 0; jd < 4; ++jd)
#pragma unroll
                        for (int reg = 0; reg < 4; ++reg)
                            o[s2][jd][reg] *= alpha[reg];
                }

                // P -> wave-private LDS [row][k] (padded; no barrier needed)
#pragma unroll
                for (int jn = 0; jn < 4; ++jn)
#pragma unroll
                    for (int reg = 0; reg < 4; ++reg)
                        Pw[(s2 * 16 + quad * 4 + reg) * PS_LD + jn * 16 + col] =
                            f2bf(p[s2][jn][reg]);
            }

            // O += P V: V-fragment read once per jd, used by BOTH strips
            bf16x8 ap[2][2];
#pragma unroll
            for (int s2 = 0; s2 < 2; ++s2) {
                ap[s2][0] = *(const bf16x8*)&Pw[(s2 * 16 + col) * PS_LD + quad * 8];
                ap[s2][1] = *(const bf16x8*)&Pw[(s2 * 16 + col) * PS_LD + 32 + quad * 8];
            }
            __builtin_amdgcn_s_setprio(1);
#pragma unroll
            for (int jd = 0; jd < 4; ++jd) {
                bf16x8 bv0 = *(const bf16x8*)&Vt[(jd * 16 + col) * 64 + cA];
                bf16x8 bv1 = *(const bf16x8*)&Vt[(jd * 16 + col) * 64 + cB];
#pragma unroll
                for (int s2 = 0; s2 < 2; ++s2) {
                    o[s2][jd] = MFMA16(ap[s2][0], bv0, o[s2][jd]);
                    o[s2][jd] = MFMA16(ap[s2][1], bv1, o[s2][jd]);
                }
            }
            __builtin_amdgcn_s_setprio(0);
        }

        // epilogue per strip: reduce l partials across 16 col-lanes, store
#pragma unroll
        for (int s2 = 0; s2 < 2; ++s2) {
#pragma unroll
            for (int off = 8; off >= 1; off >>= 1)
#pragma unroll
                for (int reg = 0; reg < 4; ++reg)
                    l_i[s2][reg] += __shfl_xor(l_i[s2][reg], off, 64);
            float inv_l[4];
#pragma unroll
            for (int reg = 0; reg < 4; ++reg) inv_l[reg] = 1.f / l_i[s2][reg];
#pragma unroll
            for (int jd = 0; jd < 4; ++jd)
#pragma unroll
                for (int reg = 0; reg < 4; ++reg) {
                    int s = q0 + s2 * 16 + quad * 4 + reg;
                    att[((size_t)(b * SEQ + s)) * DIM + h * HD + jd * 16 + col] =
                        f2bf(o[s2][jd][reg] * inv_l[reg]);
                }
        }
    }
}

// ---------------------------------------------------------------------------
// K3: out = att @ Wout^T, FP32 output. grid=(8, 64). PRE: bf16 Wout + gload.
// ---------------------------------------------------------------------------
template <bool PRE>
__global__ __launch_bounds__(256, 2) void out_gemm_kernel(
    const short* __restrict__ A, const void* __restrict__ W,
    float* __restrict__ out) {
    __shared__ __align__(16) short As[128 * 32];
    __shared__ __align__(16) short Bs[128 * 32];
    const int bm = blockIdx.y * 128, bn = blockIdx.x * 128;
    const int lane = threadIdx.x & 63, wave = threadIdx.x >> 6;
    const int quad = lane >> 4, col = lane & 15;
    const int wm = (wave & 1) * 64, wn = (wave >> 1) * 64;

    f32x4 acc[4][4];
    if constexpr (PRE)
        gemm128_lds(A, (const short*)W, 1024, As, Bs, bm, bn, acc);
    else
        gemm128_core<false, true>(A, W, 1024, As, Bs, bm, bn, acc);

#pragma unroll
    for (int i = 0; i < 4; ++i)
#pragma unroll
        for (int reg = 0; reg < 4; ++reg) {
            int    m    = bm + wm + i * 16 + quad * 4 + reg;
            size_t base = (size_t)m * DIM + bn + wn;
#pragma unroll
            for (int j = 0; j < 4; ++j)
                out[base + j * 16 + col] = acc[i][j][reg];   // FP32 store
        }
}

// ---------------------------------------------------------------------------
extern "C" void kernel_launch(void* const* d_in, const int* in_sizes, int n_in,
                              void* d_out, int out_size, void* d_ws, size_t ws_size,
                              hipStream_t stream) {
    // Pointer assignment by unique element counts:
    //   x=8388608, mask=4194304 (tril, unused), Wqkv=3145728, Wout=1048576
    const float* x    = nullptr;
    const float* Wqkv = nullptr;
    const float* Wout = nullptr;
    for (int i = 0; i < n_in; ++i) {
        switch (in_sizes[i]) {
            case 8388608: x    = (const float*)d_in[i]; break;
            case 3145728: Wqkv = (const float*)d_in[i]; break;
            case 1048576: Wout = (const float*)d_in[i]; break;
            default: break;
        }
    }
    if (!x || !Wqkv || !Wout) return;

    short* Q  = (short*)d_ws;           // 16 MiB
    short* K  = Q + BHSD;               // 16 MiB
    short* VT = K + BHSD;               // 16 MiB (V transposed [B,H,D,S])
    float* out = (float*)d_out;

    const size_t need_pre = (size_t)4 * BHSD * sizeof(short)   // Q,K,VT,att
                          + BHSD * sizeof(short)               // Xb
                          + (size_t)3145728 * sizeof(short)    // Wqkvb
                          + (size_t)1048576 * sizeof(short)    // Woutb
                          + (size_t)2 * 65536 * sizeof(float); // tables

    if (ws_size >= need_pre) {
        short* att  = VT + BHSD;
        short* Xb   = att + BHSD;
        short* Wqb  = Xb + BHSD;
        short* Wob  = Wqb + 3145728;
        float* cosT = (float*)(Wob + 1048576);
        float* sinT = cosT + 65536;

        prep_kernel<<<dim3(2048), 256, 0, stream>>>(x, Wqkv, Wout, Xb, Wqb, Wob, cosT, sinT);
        qkv_rope_kernel<true><<<dim3(24, 64), 256, 0, stream>>>(Xb, Wqb, cosT, sinT, Q, K, VT);
        attn_kernel<<<dim3(8, NH, BATCH), 256, 0, stream>>>(Q, K, VT, att);
        out_gemm_kernel<true><<<dim3(8, 64), 256, 0, stream>>>(att, Wob, out);
    } else {
        // Fallback: fp32 staging + inline RoPE.
        qkv_rope_kernel<false><<<dim3(24, 64), 256, 0, stream>>>(
            x, Wqkv, nullptr, nullptr, Q, K, VT);

        const bool direct = ws_size >= (size_t)4 * BHSD * sizeof(short);
        short* att_dst = direct ? (VT + BHSD) : (short*)d_out;
        attn_kernel<<<dim3(8, NH, BATCH), 256, 0, stream>>>(Q, K, VT, att_dst);

        short* att = att_dst;
        if (!direct) {
            att = (short*)d_ws;         // reuse Q region after K2
            hipMemcpyAsync(att, att_dst, BHSD * sizeof(short), hipMemcpyDeviceToDevice, stream);
        }
        out_gemm_kernel<false><<<dim3(8, 64), 256, 0, stream>>>(att, Wout, out);
    }
}

// Round 9
// 278.146 us; speedup vs baseline: 1.0760x; 1.0335x over previous
//
#include <hip/hip_runtime.h>
#include <math.h>

// ---------------------------------------------------------------------------
// Round 20 — K1/K3 GEMM K-loop: BK=64 double-buffer + counted vmcnt + raw
// barriers + T2 source-pre-swizzle. Tile/wave/epilogue geometry unchanged
// (128x128, 4 waves, same acc mapping). Per K-tile: vmcnt(8) [tile c landed,
// c+1 in flight] -> s_barrier -> 16 ds_read_b128 (swizzled, conflict-free) +
// 32 MFMA -> s_barrier -> stage c+2 into freed slot. Barriers halved, loads
// never drained mid-loop (T3/T4 mechanism).
//   K2 attention unchanged from round 19 (97.5 µs).
// ---------------------------------------------------------------------------

typedef __attribute__((ext_vector_type(8))) __bf16 bf16x8;
typedef __attribute__((ext_vector_type(8))) short  short8;
typedef __attribute__((ext_vector_type(4))) short  s16x4;
typedef __attribute__((ext_vector_type(4))) float  f32x4;

#define MFMA16(a, b, c) __builtin_amdgcn_mfma_f32_16x16x32_bf16((a), (b), (c), 0, 0, 0)

static constexpr int    BATCH = 4;
static constexpr int    SEQ   = 2048;
static constexpr int    DIM   = 1024;
static constexpr int    NH    = 16;
static constexpr int    HD    = 64;
static constexpr size_t BHSD  = (size_t)BATCH * NH * SEQ * HD;  // 8388608
static constexpr float  NEGINF = -1e9f;
static constexpr int    PS_LD  = 72;   // padded k-stride for Ps (16B-aligned reads)

__device__ __forceinline__ short f2bf(float f) {
    union { float f; unsigned u; } v; v.f = f;
    unsigned r = v.u + 0x7fffu + ((v.u >> 16) & 1u);  // RNE
    return (short)(r >> 16);
}

__device__ __forceinline__ short8 cvt8(const f32x4 lo, const f32x4 hi) {
    short8 r;
    r[0] = f2bf(lo[0]); r[1] = f2bf(lo[1]); r[2] = f2bf(lo[2]); r[3] = f2bf(lo[3]);
    r[4] = f2bf(hi[0]); r[5] = f2bf(hi[1]); r[6] = f2bf(hi[2]); r[7] = f2bf(hi[3]);
    return r;
}

template <bool F32>
__device__ __forceinline__ short8 ld8(const void* p, size_t row, int K, int k) {
    if constexpr (F32) {
        const float* f = (const float*)p;
        f32x4 lo = *(const f32x4*)&f[row * (size_t)K + k];
        f32x4 hi = *(const f32x4*)&f[row * (size_t)K + k + 4];
        return cvt8(lo, hi);
    } else {
        const short* s = (const short*)p;
        return *(const short8*)&s[row * (size_t)K + k];
    }
}

// async HBM->LDS, 16 B per lane. LDS dest = wave-uniform base + lane*16.
__device__ __forceinline__ void gload16(const void* g, void* lds) {
    __builtin_amdgcn_global_load_lds(
        (const __attribute__((address_space(1))) void*)g,
        (__attribute__((address_space(3))) void*)lds, 16, 0, 0);
}

// ---------------------------------------------------------------------------
// K0: one-shot bf16 conversion of X/Wqkv/Wout + RoPE trig tables.
// ---------------------------------------------------------------------------
__global__ __launch_bounds__(256) void prep_kernel(
    const float* __restrict__ X, const float* __restrict__ Wq,
    const float* __restrict__ Wo, short* __restrict__ Xb,
    short* __restrict__ Wqb, short* __restrict__ Wob,
    float* __restrict__ cosT, float* __restrict__ sinT) {
    const int stride = gridDim.x * blockDim.x;
    for (int idx = blockIdx.x * blockDim.x + threadIdx.x; idx < 3211264; idx += stride) {
        if (idx < 3145728) {
            const float* src; short* dst; int off;
            if (idx < 2097152)      { src = X;  dst = Xb;  off = idx; }
            else if (idx < 2883584) { src = Wq; dst = Wqb; off = idx - 2097152; }
            else                    { src = Wo; dst = Wob; off = idx - 2883584; }
            f32x4 v = *(const f32x4*)&src[(size_t)off * 4];
            s16x4 r;
            r[0] = f2bf(v[0]); r[1] = f2bf(v[1]); r[2] = f2bf(v[2]); r[3] = f2bf(v[3]);
            *(s16x4*)&dst[(size_t)off * 4] = r;
        } else {
            int r = idx - 3145728;              // 0..65535
            int s = r >> 5, d = r & 31;
            float ang = (float)s * __expf(-0.28782313662425574f * (float)d);
            float sn, cs;
            sincosf(ang, &sn, &cs);
            cosT[r] = cs; sinT[r] = sn;
        }
    }
}

// ---------------------------------------------------------------------------
// GEMM core (fallback, reg-staged): C(128x128) += A(128xK) * B(128xK)^T.
// Uses only the first 128*32 shorts of As/Bs.
// ---------------------------------------------------------------------------
template <bool AF32, bool BF32>
__device__ __forceinline__ void gemm128_core(
    const void* __restrict__ A, const void* __restrict__ B, int K,
    short* As, short* Bs, int bm, int bn, f32x4 acc[4][4]) {
    const int tid  = threadIdx.x;
    const int lane = tid & 63;
    const int wave = tid >> 6;
    const int quad = lane >> 4;
    const int col  = lane & 15;
    const int wm   = (wave & 1) * 64;
    const int wn   = (wave >> 1) * 64;

    const int r0 = tid >> 2;
    const int r1 = (tid + 256) >> 2;
    const int ko = (tid & 3) * 8;

#pragma unroll
    for (int i = 0; i < 4; ++i)
#pragma unroll
        for (int j = 0; j < 4; ++j) acc[i][j] = f32x4{0.f, 0.f, 0.f, 0.f};

#pragma unroll 1
    for (int k0 = 0; k0 < K; k0 += 32) {
        short8 a0 = ld8<AF32>(A, (size_t)(bm + r0), K, k0 + ko);
        short8 a1 = ld8<AF32>(A, (size_t)(bm + r1), K, k0 + ko);
        short8 b0 = ld8<BF32>(B, (size_t)(bn + r0), K, k0 + ko);
        short8 b1 = ld8<BF32>(B, (size_t)(bn + r1), K, k0 + ko);
        __syncthreads();
        *(short8*)&As[tid * 8]         = a0;
        *(short8*)&As[(tid + 256) * 8] = a1;
        *(short8*)&Bs[tid * 8]         = b0;
        *(short8*)&Bs[(tid + 256) * 8] = b1;
        __syncthreads();

        bf16x8 af[4], bfr[4];
#pragma unroll
        for (int i = 0; i < 4; ++i)
            af[i] = *(const bf16x8*)&As[(wm + i * 16 + col) * 32 + quad * 8];
#pragma unroll
        for (int j = 0; j < 4; ++j)
            bfr[j] = *(const bf16x8*)&Bs[(wn + j * 16 + col) * 32 + quad * 8];
#pragma unroll
        for (int i = 0; i < 4; ++i)
#pragma unroll
            for (int j = 0; j < 4; ++j)
                acc[i][j] = MFMA16(af[i], bfr[j], acc[i][j]);
    }
}

// ---------------------------------------------------------------------------
// GEMM core v2 (bf16): BK=64, double-buffered gload_lds, counted vmcnt,
// raw barriers, source-pre-swizzled LDS (T2, G21/m173 pattern).
// LDS per operand: [2 slots][128 rows][64 k] bf16 (16 KB/slot).
//   staging : thread tid, inst q: row = q*32 + (tid>>3), phys chunk = tid&7,
//             logical chunk = (tid&7) ^ (row&7)  -> source k-offset swizzled,
//             dest linear = slot*8192 + q*2048 + wave*512 (+lane*16B by HW).
//   frag read: row r, k-chunk (kk*4+quad): phys = (kk*4+quad) ^ (r&7)
//             (r&7 == col&7) -> 8 pc-slots x 8 lanes = minimum-cycle b128.
// vmcnt ledger: prologue stages tiles 0,1 (16 loads/thread); per-tile wait
// vmcnt(8) -> tile c landed, c+1 in flight; after compute+barrier stage c+2
// (8 loads) into freed slot; last tile waits vmcnt(0).
// ---------------------------------------------------------------------------
__device__ __forceinline__ void gemm128_p2(
    const short* __restrict__ A, const short* __restrict__ B, int K,
    short* As, short* Bs, int bm, int bn, f32x4 acc[4][4]) {
    const int tid  = threadIdx.x;
    const int lane = tid & 63;
    const int wave = tid >> 6;
    const int quad = lane >> 4;
    const int col  = lane & 15;
    const int wm   = (wave & 1) * 64;
    const int wn   = (wave >> 1) * 64;

    const int nt = K >> 6;                        // K-tiles of 64
    const int rr = tid >> 3;                      // staging row 0..31 (+q*32)
    const int swk = (((tid & 7) ^ (rr & 7)) << 3);// swizzled src k-off (shorts)
    const short* Ab = &A[(size_t)(bm + rr) * K + swk];
    const short* Bb = &B[(size_t)(bn + rr) * K + swk];

#pragma unroll
    for (int i = 0; i < 4; ++i)
#pragma unroll
        for (int j = 0; j < 4; ++j) acc[i][j] = f32x4{0.f, 0.f, 0.f, 0.f};

    // stage K-tile c into slot (c&1): 4 A + 4 B gload16 per thread
#define STAGE_TILE(c)                                                         \
    {                                                                         \
        const int s_ = (c) & 1;                                               \
        const int k0_ = (c) << 6;                                             \
        _Pragma("unroll")                                                     \
        for (int q = 0; q < 4; ++q) {                                         \
            gload16(Ab + (size_t)(q * 32) * K + k0_,                          \
                    &As[s_ * 8192 + q * 2048 + wave * 512]);                  \
            gload16(Bb + (size_t)(q * 32) * K + k0_,                          \
                    &Bs[s_ * 8192 + q * 2048 + wave * 512]);                  \
        }                                                                     \
    }

    STAGE_TILE(0);
    STAGE_TILE(1);

    const int pc0 = ((quad) ^ (col & 7)) << 3;      // kk=0 phys chunk (shorts)
    const int pc1 = ((4 | quad) ^ (col & 7)) << 3;  // kk=1

#pragma unroll 1
    for (int c = 0; c < nt; ++c) {
        const int s = c & 1;
        if (c + 1 < nt) { asm volatile("s_waitcnt vmcnt(8)" ::: "memory"); }
        else            { asm volatile("s_waitcnt vmcnt(0)" ::: "memory"); }
        __builtin_amdgcn_s_barrier();              // tile c staged for all waves

        const short* Asl = &As[s * 8192];
        const short* Bsl = &Bs[s * 8192];
        bf16x8 af[4][2], bfr[4][2];
#pragma unroll
        for (int i = 0; i < 4; ++i) {
            const int r = (wm + i * 16 + col) * 64;
            af[i][0] = *(const bf16x8*)&Asl[r + pc0];
            af[i][1] = *(const bf16x8*)&Asl[r + pc1];
        }
#pragma unroll
        for (int j = 0; j < 4; ++j) {
            const int r = (wn + j * 16 + col) * 64;
            bfr[j][0] = *(const bf16x8*)&Bsl[r + pc0];
            bfr[j][1] = *(const bf16x8*)&Bsl[r + pc1];
        }
#pragma unroll
        for (int kk = 0; kk < 2; ++kk)
#pragma unroll
            for (int i = 0; i < 4; ++i)
#pragma unroll
                for (int j = 0; j < 4; ++j)
                    acc[i][j] = MFMA16(af[i][kk], bfr[j][kk], acc[i][j]);

        __builtin_amdgcn_s_barrier();              // all reads of slot done
        if (c + 2 < nt) STAGE_TILE(c + 2);         // overwrite freed slot
    }
#undef STAGE_TILE
}

// ---------------------------------------------------------------------------
// K1: QKV GEMM + RoPE. grid=(24, 64). Q,K row-major [B,H,S,D]; V transposed
// [B,H,D,S]. PRE: bf16 inputs (p2 core) + table RoPE.
// ---------------------------------------------------------------------------
template <bool PRE>
__global__ __launch_bounds__(256, 2) void qkv_rope_kernel(
    const void* __restrict__ X, const void* __restrict__ W,
    const float* __restrict__ cosT, const float* __restrict__ sinT,
    short* __restrict__ Qo, short* __restrict__ Ko, short* __restrict__ VT) {
    __shared__ __align__(16) short As[2 * 8192];
    __shared__ __align__(16) short Bs[2 * 8192];
    const int bm = blockIdx.y * 128, bn = blockIdx.x * 128;
    const int lane = threadIdx.x & 63, wave = threadIdx.x >> 6;
    const int quad = lane >> 4, col = lane & 15;
    const int wm = (wave & 1) * 64, wn = (wave >> 1) * 64;

    f32x4 acc[4][4];
    if constexpr (PRE)
        gemm128_p2((const short*)X, (const short*)W, 1024, As, Bs, bm, bn, acc);
    else
        gemm128_core<true, true>(X, W, 1024, As, Bs, bm, bn, acc);

    const int n0    = bn + wn;       // 64-aligned -> which/h wave-uniform
    const int which = n0 >> 10;      // 0=q 1=k 2=v
    const int h     = (n0 >> 6) & 15;

    if (which == 2) {
        // V^T: VT[((b*NH+h)*HD + d)*SEQ + s], 4 consecutive s per 8B store
#pragma unroll
        for (int i = 0; i < 4; ++i) {
            int    m = bm + wm + i * 16 + quad * 4;    // s of reg 0
            int    b = m >> 11, s = m & 2047;
            size_t rowb = (size_t)(b * NH + h) * HD;
#pragma unroll
            for (int j = 0; j < 4; ++j) {
                int   d = j * 16 + col;
                s16x4 pk;
                pk[0] = f2bf(acc[i][j][0]); pk[1] = f2bf(acc[i][j][1]);
                pk[2] = f2bf(acc[i][j][2]); pk[3] = f2bf(acc[i][j][3]);
                *(s16x4*)&VT[(rowb + d) * SEQ + s] = pk;
            }
        }
    } else {
        short* dst = which ? Ko : Qo;
#pragma unroll
        for (int i = 0; i < 4; ++i)
#pragma unroll
            for (int reg = 0; reg < 4; ++reg) {
                int    m = bm + wm + i * 16 + quad * 4 + reg;
                int    b = m >> 11, s = m & 2047;
                size_t base = ((size_t)(b * NH + h) * SEQ + s) * HD;
#pragma unroll
                for (int j = 0; j < 2; ++j) {
                    int   d1 = j * 16 + col;                        // 0..31
                    float sn, cs;
                    if constexpr (PRE) {
                        cs = cosT[(s << 5) + d1];
                        sn = sinT[(s << 5) + d1];
                    } else {
                        float inv = __expf(-0.28782313662425574f * (float)d1);
                        sincosf((float)s * inv, &sn, &cs);
                    }
                    float x1 = acc[i][j][reg];
                    float x2 = acc[i][j + 2][reg];
                    dst[base + d1]      = f2bf(x1 * cs - x2 * sn);
                    dst[base + d1 + 32] = f2bf(x1 * sn + x2 * cs);
                }
            }
    }
}

// ---------------------------------------------------------------------------
// K2: causal flash attention (round-19 version, unchanged). 256 threads /
// 4 waves; wave owns 32 q-rows (two strips); QBLK=128; pairing {bx,15-bx};
// XOR-swizzled Kt/Vt; defer-max THR=8 + per-lane partial l_i; setprio.
// ---------------------------------------------------------------------------
__global__ __launch_bounds__(256, 2) void attn_kernel(
    const short* __restrict__ Q, const short* __restrict__ K,
    const short* __restrict__ VT, short* __restrict__ att) {
    const int b = blockIdx.z, h = blockIdx.y;
    const int tid = threadIdx.x, wave = tid >> 6, lane = tid & 63;
    const int quad = lane >> 4, col = lane & 15;
    const size_t hoff = (size_t)(b * NH + h) * SEQ * HD;
    const short* Qp  = Q + hoff;
    const short* Kp  = K + hoff;
    const short* VTp = VT + hoff;   // [HD][SEQ]

    __shared__ __align__(16) short Kt[64 * 64];        // [t][d], swizzled
    __shared__ __align__(16) short Vt[64 * 64];        // [d][t], swizzled
    __shared__ __align__(16) short Ps[4 * 32 * PS_LD]; // per-wave P [32][k], padded

    const int r0 = tid >> 3;            // 0..31
    const int r1 = r0 + 32;             // 32..63  (r1&7 == r0&7)
    const int c8 = (tid & 7) * 8;
    const int cs = c8 ^ ((r0 & 7) << 3);            // swizzled store column
    const int swc = (col & 7) << 3;
    const int cA  = (quad * 8) ^ swc;               // first half of row
    const int cB  = (32 + quad * 8) ^ swc;          // second half of row
    short* Pw = &Ps[wave * 32 * PS_LD];

#pragma unroll 1
    for (int pass = 0; pass < 2; ++pass) {
        const int qt   = pass ? 15 - (int)blockIdx.x : (int)blockIdx.x;
        const int q0   = qt * 128 + wave * 32;      // wave's first q-row
        const int tmax = 2 * qt + 1;

        // Q fragments for both strips (s2 = 0,1)
        bf16x8 aq[2][2];
#pragma unroll
        for (int s2 = 0; s2 < 2; ++s2) {
            aq[s2][0] = *(const bf16x8*)&Qp[(q0 + s2 * 16 + col) * HD + quad * 8];
            aq[s2][1] = *(const bf16x8*)&Qp[(q0 + s2 * 16 + col) * HD + 32 + quad * 8];
        }

        float m_i[2][4], l_i[2][4];
        f32x4 o[2][4];
#pragma unroll
        for (int s2 = 0; s2 < 2; ++s2)
#pragma unroll
            for (int rr = 0; rr < 4; ++rr) {
                m_i[s2][rr] = NEGINF; l_i[s2][rr] = 0.f;
                o[s2][rr] = f32x4{0.f, 0.f, 0.f, 0.f};
            }

        // prefetch tile 0
        short8 ka = *(const short8*)&Kp[r0 * HD + c8];
        short8 kb = *(const short8*)&Kp[r1 * HD + c8];
        short8 va = *(const short8*)&VTp[(size_t)r0 * SEQ + c8];
        short8 vb = *(const short8*)&VTp[(size_t)r1 * SEQ + c8];

#pragma unroll 1
        for (int t = 0; t <= tmax; ++t) {
            const int kt = t * 64;
            __syncthreads();                       // prev iter's LDS reads done
            *(short8*)&Kt[r0 * 64 + cs] = ka;
            *(short8*)&Kt[r1 * 64 + cs] = kb;
            *(short8*)&Vt[r0 * 64 + cs] = va;
            *(short8*)&Vt[r1 * 64 + cs] = vb;
            __syncthreads();                       // tile staged

            if (t < tmax) {                        // prefetch next tile
                const int kn = kt + 64;
                ka = *(const short8*)&Kp[(kn + r0) * HD + c8];
                kb = *(const short8*)&Kp[(kn + r1) * HD + c8];
                va = *(const short8*)&VTp[(size_t)r0 * SEQ + kn + c8];
                vb = *(const short8*)&VTp[(size_t)r1 * SEQ + kn + c8];
            }

            if (kt > q0 + 31) continue;            // wave fully masked

            // S = Q K^T / 8: K-fragment read once per jn, used by BOTH strips
            float p[2][4][4];  // [s2][jn][reg]
            __builtin_amdgcn_s_setprio(1);
#pragma unroll
            for (int jn = 0; jn < 4; ++jn) {
                bf16x8 b0 = *(const bf16x8*)&Kt[(jn * 16 + col) * 64 + cA];
                bf16x8 b1 = *(const bf16x8*)&Kt[(jn * 16 + col) * 64 + cB];
#pragma unroll
                for (int s2 = 0; s2 < 2; ++s2) {
                    f32x4 s = f32x4{0.f, 0.f, 0.f, 0.f};
                    s = MFMA16(aq[s2][0], b0, s);
                    s = MFMA16(aq[s2][1], b1, s);
                    if (t >= 2 * qt) {             // wave-uniform branch
#pragma unroll
                        for (int reg = 0; reg < 4; ++reg) {
                            int qr = q0 + s2 * 16 + quad * 4 + reg;  // global row
                            int kc = kt + jn * 16 + col;             // global col
                            p[s2][jn][reg] = (kc <= qr) ? s[reg] * 0.125f : NEGINF;
                        }
                    } else {
#pragma unroll
                        for (int reg = 0; reg < 4; ++reg)
                            p[s2][jn][reg] = s[reg] * 0.125f;
                    }
                }
            }
            __builtin_amdgcn_s_setprio(0);

            // --- softmax per strip: defer-max (THR=8) + per-lane partial l ---
#pragma unroll
            for (int s2 = 0; s2 < 2; ++s2) {
                float lm[4];
#pragma unroll
                for (int reg = 0; reg < 4; ++reg)
                    lm[reg] = fmaxf(fmaxf(p[s2][0][reg], p[s2][1][reg]),
                                    fmaxf(p[s2][2][reg], p[s2][3][reg]));
                int ok = (lm[0] <= m_i[s2][0] + 8.f) & (lm[1] <= m_i[s2][1] + 8.f) &
                         (lm[2] <= m_i[s2][2] + 8.f) & (lm[3] <= m_i[s2][3] + 8.f);
                if (__all(ok)) {
#pragma unroll
                    for (int reg = 0; reg < 4; ++reg) {
                        float rs = 0.f;
#pragma unroll
                        for (int jn = 0; jn < 4; ++jn) {
                            p[s2][jn][reg] = __expf(p[s2][jn][reg] - m_i[s2][reg]);
                            rs += p[s2][jn][reg];
                        }
                        l_i[s2][reg] += rs;
                    }
                } else {
                    float alpha[4];
#pragma unroll
                    for (int reg = 0; reg < 4; ++reg) {
                        float mx = lm[reg];
#pragma unroll
                        for (int off = 8; off >= 1; off >>= 1)
                            mx = fmaxf(mx, __shfl_xor(mx, off, 64));
                        float mn   = fmaxf(m_i[s2][reg], mx);
                        alpha[reg] = __expf(m_i[s2][reg] - mn);
                        float rs = 0.f;
#pragma unroll
                        for (int jn = 0; jn < 4; ++jn) {
                            p[s2][jn][reg] = __expf(p[s2][jn][reg] - mn);
                            rs += p[s2][jn][reg];
                        }
                        l_i[s2][reg] = l_i[s2][reg] * alpha[reg] + rs;
                        m_i[s2][reg] = mn;
                    }
#pragma unroll
                    for (int jd = 0; jd < 4; ++jd)
#pragma unroll
                        for (int reg = 0; reg < 4; ++reg)
                            o[s2][jd][reg] *= alpha[reg];
                }

                // P -> wave-private LDS [row][k] (padded; no barrier needed)
#pragma unroll
                for (int jn = 0; jn < 4; ++jn)
#pragma unroll
                    for (int reg = 0; reg < 4; ++reg)
                        Pw[(s2 * 16 + quad * 4 + reg) * PS_LD + jn * 16 + col] =
                            f2bf(p[s2][jn][reg]);
            }

            // O += P V: V-fragment read once per jd, used by BOTH strips
            bf16x8 ap[2][2];
#pragma unroll
            for (int s2 = 0; s2 < 2; ++s2) {
                ap[s2][0] = *(const bf16x8*)&Pw[(s2 * 16 + col) * PS_LD + quad * 8];
                ap[s2][1] = *(const bf16x8*)&Pw[(s2 * 16 + col) * PS_LD + 32 + quad * 8];
            }
            __builtin_amdgcn_s_setprio(1);
#pragma unroll
            for (int jd = 0; jd < 4; ++jd) {
                bf16x8 bv0 = *(const bf16x8*)&Vt[(jd * 16 + col) * 64 + cA];
                bf16x8 bv1 = *(const bf16x8*)&Vt[(jd * 16 + col) * 64 + cB];
#pragma unroll
                for (int s2 = 0; s2 < 2; ++s2) {
                    o[s2][jd] = MFMA16(ap[s2][0], bv0, o[s2][jd]);
                    o[s2][jd] = MFMA16(ap[s2][1], bv1, o[s2][jd]);
                }
            }
            __builtin_amdgcn_s_setprio(0);
        }

        // epilogue per strip: reduce l partials across 16 col-lanes, store
#pragma unroll
        for (int s2 = 0; s2 < 2; ++s2) {
#pragma unroll
            for (int off = 8; off >= 1; off >>= 1)
#pragma unroll
                for (int reg = 0; reg < 4; ++reg)
                    l_i[s2][reg] += __shfl_xor(l_i[s2][reg], off, 64);
            float inv_l[4];
#pragma unroll
            for (int reg = 0; reg < 4; ++reg) inv_l[reg] = 1.f / l_i[s2][reg];
#pragma unroll
            for (int jd = 0; jd < 4; ++jd)
#pragma unroll
                for (int reg = 0; reg < 4; ++reg) {
                    int s = q0 + s2 * 16 + quad * 4 + reg;
                    att[((size_t)(b * SEQ + s)) * DIM + h * HD + jd * 16 + col] =
                        f2bf(o[s2][jd][reg] * inv_l[reg]);
                }
        }
    }
}

// ---------------------------------------------------------------------------
// K3: out = att @ Wout^T, FP32 output. grid=(8, 64). PRE: bf16 Wout + p2 core.
// ---------------------------------------------------------------------------
template <bool PRE>
__global__ __launch_bounds__(256, 2) void out_gemm_kernel(
    const short* __restrict__ A, const void* __restrict__ W,
    float* __restrict__ out) {
    __shared__ __align__(16) short As[2 * 8192];
    __shared__ __align__(16) short Bs[2 * 8192];
    const int bm = blockIdx.y * 128, bn = blockIdx.x * 128;
    const int lane = threadIdx.x & 63, wave = threadIdx.x >> 6;
    const int quad = lane >> 4, col = lane & 15;
    const int wm = (wave & 1) * 64, wn = (wave >> 1) * 64;

    f32x4 acc[4][4];
    if constexpr (PRE)
        gemm128_p2(A, (const short*)W, 1024, As, Bs, bm, bn, acc);
    else
        gemm128_core<false, true>(A, W, 1024, As, Bs, bm, bn, acc);

#pragma unroll
    for (int i = 0; i < 4; ++i)
#pragma unroll
        for (int reg = 0; reg < 4; ++reg) {
            int    m    = bm + wm + i * 16 + quad * 4 + reg;
            size_t base = (size_t)m * DIM + bn + wn;
#pragma unroll
            for (int j = 0; j < 4; ++j)
                out[base + j * 16 + col] = acc[i][j][reg];   // FP32 store
        }
}

// ---------------------------------------------------------------------------
extern "C" void kernel_launch(void* const* d_in, const int* in_sizes, int n_in,
                              void* d_out, int out_size, void* d_ws, size_t ws_size,
                              hipStream_t stream) {
    // Pointer assignment by unique element counts:
    //   x=8388608, mask=4194304 (tril, unused), Wqkv=3145728, Wout=1048576
    const float* x    = nullptr;
    const float* Wqkv = nullptr;
    const float* Wout = nullptr;
    for (int i = 0; i < n_in; ++i) {
        switch (in_sizes[i]) {
            case 8388608: x    = (const float*)d_in[i]; break;
            case 3145728: Wqkv = (const float*)d_in[i]; break;
            case 1048576: Wout = (const float*)d_in[i]; break;
            default: break;
        }
    }
    if (!x || !Wqkv || !Wout) return;

    short* Q  = (short*)d_ws;           // 16 MiB
    short* K  = Q + BHSD;               // 16 MiB
    short* VT = K + BHSD;               // 16 MiB (V transposed [B,H,D,S])
    float* out = (float*)d_out;

    const size_t need_pre = (size_t)4 * BHSD * sizeof(short)   // Q,K,VT,att
                          + BHSD * sizeof(short)               // Xb
                          + (size_t)3145728 * sizeof(short)    // Wqkvb
                          + (size_t)1048576 * sizeof(short)    // Woutb
                          + (size_t)2 * 65536 * sizeof(float); // tables

    if (ws_size >= need_pre) {
        short* att  = VT + BHSD;
        short* Xb   = att + BHSD;
        short* Wqb  = Xb + BHSD;
        short* Wob  = Wqb + 3145728;
        float* cosT = (float*)(Wob + 1048576);
        float* sinT = cosT + 65536;

        prep_kernel<<<dim3(2048), 256, 0, stream>>>(x, Wqkv, Wout, Xb, Wqb, Wob, cosT, sinT);
        qkv_rope_kernel<true><<<dim3(24, 64), 256, 0, stream>>>(Xb, Wqb, cosT, sinT, Q, K, VT);
        attn_kernel<<<dim3(8, NH, BATCH), 256, 0, stream>>>(Q, K, VT, att);
        out_gemm_kernel<true><<<dim3(8, 64), 256, 0, stream>>>(att, Wob, out);
    } else {
        // Fallback: fp32 staging + inline RoPE.
        qkv_rope_kernel<false><<<dim3(24, 64), 256, 0, stream>>>(
            x, Wqkv, nullptr, nullptr, Q, K, VT);

        const bool direct = ws_size >= (size_t)4 * BHSD * sizeof(short);
        short* att_dst = direct ? (VT + BHSD) : (short*)d_out;
        attn_kernel<<<dim3(8, NH, BATCH), 256, 0, stream>>>(Q, K, VT, att_dst);

        short* att = att_dst;
        if (!direct) {
            att = (short*)d_ws;         // reuse Q region after K2
            hipMemcpyAsync(att, att_dst, BHSD * sizeof(short), hipMemcpyDeviceToDevice, stream);
        }
        out_gemm_kernel<false><<<dim3(8, 64), 256, 0, stream>>>(att, Wout, out);
    }
}